// Round 12
// baseline (87.463 us; speedup 1.0000x reference)
//
#include <hip/hip_runtime.h>

typedef unsigned short ushort_t;
typedef __bf16 bf16x8 __attribute__((ext_vector_type(8)));
typedef float f32x4 __attribute__((ext_vector_type(4)));
typedef void __attribute__((address_space(1))) gvoid_t;
typedef void __attribute__((address_space(3))) lvoid_t;

__device__ __forceinline__ float bflo(unsigned u) { return __builtin_bit_cast(float, u << 16); }
__device__ __forceinline__ float bfhi(unsigned u) { return __builtin_bit_cast(float, u & 0xffff0000u); }
__device__ __forceinline__ float bf2f(ushort_t v) {
  return __builtin_bit_cast(float, ((unsigned)v) << 16);
}
__device__ __forceinline__ unsigned f2bf_bits(float f) {
  unsigned u = __builtin_bit_cast(unsigned, f);
  return (u + 0x7fffu + ((u >> 16) & 1u)) >> 16;
}
__device__ __forceinline__ ushort_t f2bf(float f) { return (ushort_t)f2bf_bits(f); }

// ---------------- prep: weight (o,c,k) f32 -> wb[k][o][c] bf16 ----------------
__global__ __launch_bounds__(256) void k_prep_w(const float* __restrict__ w,
                                                ushort_t* __restrict__ wb) {
  const int idx = blockIdx.x * 256 + threadIdx.x;  // (o,c) pair, 65536 total
  const float* src = w + (size_t)idx * 9;
  #pragma unroll
  for (int k = 0; k < 9; ++k)
    wb[(k << 16) + idx] = f2bf(src[k]);
}

// ---------------- prep: x (b,c,h,w) f32 -> xt[b][h][w][c] bf16 ----------------
__global__ __launch_bounds__(256) void k_prep_x(const float* __restrict__ x,
                                                ushort_t* __restrict__ xt) {
  __shared__ ushort_t tile[64][68];
  const int bid = blockIdx.x;             // 4b * 4ct * 64pt = 1024
  const int b = bid >> 8;
  const int ct = (bid >> 6) & 3;
  const int pt = bid & 63;
  const int t = threadIdx.x;
  const float* xb = x + ((size_t)(b * 256 + ct * 64)) * 4096 + pt * 64;
  #pragma unroll
  for (int i = 0; i < 16; ++i) {
    const int idx = t + 256 * i;
    const int c_l = idx >> 6, p_l = idx & 63;
    tile[c_l][p_l] = f2bf(xb[(size_t)c_l * 4096 + p_l]);
  }
  __syncthreads();
  ushort_t* xo = xt + ((size_t)(b * 4096 + pt * 64)) * 256 + ct * 64;
  #pragma unroll
  for (int i = 0; i < 16; ++i) {
    const int idx = t + 256 * i;
    const int p_l = idx >> 6, c_l = idx & 63;
    xo[(size_t)p_l * 256 + c_l] = tile[c_l][p_l];
  }
}

// bilinear meta for one (h, w, tap)
struct SMeta {
  float w00, w01, w10, w11;
  int i00, i01, i10, i11;
};
__device__ __forceinline__ SMeta meta_for(int h, int gw, int k, float oy, float ox) {
  SMeta m;
  const float py = (float)(h - 1 + k / 3) + oy;
  const float px = (float)(gw - 1 + k % 3) + ox;
  const float fy = floorf(py), fx = floorf(px);
  const float ly = py - fy, lx = px - fx;
  const int iy0 = (int)fy, ix0 = (int)fx;
  const float vy0 = (iy0 >= 0 && iy0 < 64) ? 1.f : 0.f;
  const float vy1 = (iy0 >= -1 && iy0 < 63) ? 1.f : 0.f;
  const float vx0 = (ix0 >= 0 && ix0 < 64) ? 1.f : 0.f;
  const float vx1 = (ix0 >= -1 && ix0 < 63) ? 1.f : 0.f;
  m.w00 = (1.f - ly) * (1.f - lx) * vy0 * vx0;
  m.w01 = (1.f - ly) * lx * vy0 * vx1;
  m.w10 = ly * (1.f - lx) * vy1 * vx0;
  m.w11 = ly * lx * vy1 * vx1;
  const int cy0 = min(max(iy0, 0), 63), cy1 = min(max(iy0 + 1, 0), 63);
  const int cx0 = min(max(ix0, 0), 63), cx1 = min(max(ix0 + 1, 0), 63);
  m.i00 = (cy0 * 64 + cx0) * 256;
  m.i01 = (cy0 * 64 + cx1) * 256;
  m.i10 = (cy1 * 64 + cx0) * 256;
  m.i11 = (cy1 * 64 + cx1) * 256;
  return m;
}

__device__ __forceinline__ unsigned lerp_pack(unsigned a, unsigned b, unsigned c, unsigned d,
                                              float w00, float w01, float w10, float w11) {
  float lo = w00 * bflo(a) + w01 * bflo(b) + w10 * bflo(c) + w11 * bflo(d);
  float hi = w00 * bfhi(a) + w01 * bfhi(b) + w10 * bfhi(c) + w11 * bfhi(d);
  return f2bf_bits(lo) | (f2bf_bits(hi) << 16);
}

// ---- K-half GEMM body: 18 chunks (CB=KH*18 .. +17), chunk c: tap c>>2,
// cols (c&3)*64. dist-1 prefetch of BOTH gathers and B at period start; the
// publish is __syncthreads()'s own vmcnt(0)+lgkmcnt(0) drain (robust to
// compiler spills and load reordering — no manual waitcnt ledger at all;
// loads get the whole ~1000cy compute phase to land, so the drain is cheap).
template <int KH>
__device__ __forceinline__ void run_gemm(const float* __restrict__ offb,
                                         const ushort_t* __restrict__ xtb,
                                         const ushort_t* __restrict__ wb,
                                         ushort_t* Ab, ushort_t* Bb,
                                         int h, int s_w, int c8, int t,
                                         int wm, int wn, int wq, int wr,
                                         f32x4 (&acc)[2][4]) {
  // this half's 5 taps of offsets (KH=0: taps 0..4, KH=1: taps 4..8)
  float oy[5], ox[5];
  #pragma unroll
  for (int i = 0; i < 5; ++i) {
    oy[i] = offb[(2 * (KH * 4 + i)) * 4096];
    ox[i] = offb[(2 * (KH * 4 + i) + 1) * 4096];
  }

#define GATHER(N)                                                \
  {                                                              \
    const int c_ = KH * 18 + (N);                                \
    const int tap_ = c_ >> 2;                                    \
    const int loc_ = tap_ - KH * 4;                              \
    const int c0_ = (c_ & 3) << 6;                               \
    m = meta_for(h, s_w, tap_, oy[loc_], ox[loc_]);              \
    const int cc_ = c0_ + c8 * 8;                                \
    q00 = *(const uint4*)(xtb + m.i00 + cc_);                    \
    q01 = *(const uint4*)(xtb + m.i01 + cc_);                    \
    q10 = *(const uint4*)(xtb + m.i10 + cc_);                    \
    q11 = *(const uint4*)(xtb + m.i11 + cc_);                    \
  }

#define B_ISSUE(N, BUF)                                                                        \
  {                                                                                            \
    const int c_ = KH * 18 + (N);                                                              \
    const int tap_ = c_ >> 2;                                                                  \
    const int c0_ = (c_ & 3) << 6;                                                             \
    _Pragma("unroll") for (int i_ = 0; i_ < 4; ++i_) {                                         \
      const int idx_ = i_ * 512 + t;                                                           \
      const int row_ = idx_ >> 3, slot_ = idx_ & 7;                                            \
      const ushort_t* g_ = wb + (tap_ << 16) + row_ * 256 + c0_ + ((slot_ ^ (row_ & 7)) << 3); \
      __builtin_amdgcn_global_load_lds(                                                        \
          (gvoid_t*)g_, (lvoid_t*)((char*)Bb + (BUF) * 32768 + idx_ * 16), 16, 0, 0);          \
    }                                                                                          \
  }

#define A_WRITE(BUF)                                                         \
  {                                                                          \
    uint4 r;                                                                 \
    r.x = lerp_pack(q00.x, q01.x, q10.x, q11.x, m.w00, m.w01, m.w10, m.w11); \
    r.y = lerp_pack(q00.y, q01.y, q10.y, q11.y, m.w00, m.w01, m.w10, m.w11); \
    r.z = lerp_pack(q00.z, q01.z, q10.z, q11.z, m.w00, m.w01, m.w10, m.w11); \
    r.w = lerp_pack(q00.w, q01.w, q10.w, q11.w, m.w00, m.w01, m.w10, m.w11); \
    *(uint4*)&Ab[(BUF) * 4096 + s_w * 64 + ((c8 ^ (s_w & 7)) << 3)] = r;     \
  }

  // ---- prologue: stage chunk 0 into buffer 0; syncthreads publishes ----
  {
    SMeta m;
    uint4 q00, q01, q10, q11;
    B_ISSUE(0, 0);
    GATHER(0);
    A_WRITE(0);
  }
  __syncthreads();

  // ---- 18 periods, fully unrolled ----
  #pragma unroll
  for (int n = 0; n < 18; ++n) {
    const int cur = n & 1;
    const int nb = cur ^ 1;
    SMeta m;
    uint4 q00, q01, q10, q11;
    // 1. prefetch next chunk at period start (whole compute phase to land)
    if (n < 17) {
      B_ISSUE(n + 1, nb);
      GATHER(n + 1);
    }
    // 2. MFMA chunk n from buf[cur]
    #pragma unroll
    for (int ks = 0; ks < 2; ++ks) {
      bf16x8 af[2], bfr[4];
      #pragma unroll
      for (int tm = 0; tm < 2; ++tm) {
        const int row = wm * 32 + tm * 16 + wr;
        const int slot = (ks * 4 + wq) ^ (row & 7);
        af[tm] = *(const bf16x8*)&Ab[cur * 4096 + row * 64 + slot * 8];
      }
      #pragma unroll
      for (int tn = 0; tn < 4; ++tn) {
        const int row = wn * 64 + tn * 16 + wr;
        const int slot = (ks * 4 + wq) ^ (row & 7);
        bfr[tn] = *(const bf16x8*)&Bb[cur * 16384 + row * 64 + slot * 8];
      }
      #pragma unroll
      for (int tm = 0; tm < 2; ++tm)
        #pragma unroll
        for (int tn = 0; tn < 4; ++tn)
          acc[tm][tn] =
              __builtin_amdgcn_mfma_f32_16x16x32_bf16(af[tm], bfr[tn], acc[tm][tn], 0, 0, 0);
    }
    // 3. pack A(n+1) (compiler inserts the exact waits for the gather regs)
    if (n < 17) {
      A_WRITE(nb);
      __syncthreads();  // vmcnt(0)+lgkmcnt(0) drain = publish of A(n+1), B(n+1)
    }
  }
#undef GATHER
#undef B_ISSUE
#undef A_WRITE
}

// ---------------- fused deform-sample + GEMM, K-split bf16 partials ----------------
// grid = 512: rowid=bid&255 -> (b,h) via XCD swizzle; kh=bid>>8 (256 ≡ 0 mod 8
// keeps both K-halves of a row on the same XCD/L2). Each block: BM=64, BN=256,
// 8 waves, 18 chunks of its K-half. LDS 80KB (A 2x8KB + B 2x32KB) -> 2
// INDEPENDENT blocks/CU: no shared barrier between them, so their phase trains
// interleave on the SIMDs (m114 mechanism — the overlap intra-block splits
// failed to achieve in R4/R8/R10). Plain __launch_bounds__(512): VGPR floats
// (~110), no forced spills. No manual waitcnt anywhere (R8/R11 lesson).
__global__ __launch_bounds__(512) void k_gemm(const float* __restrict__ off,
                                              const ushort_t* __restrict__ xt,
                                              const ushort_t* __restrict__ wb,
                                              ushort_t* __restrict__ y0,
                                              ushort_t* __restrict__ y1) {
  __shared__ __attribute__((aligned(16))) ushort_t Abuf[2][64 * 64];   // 16KB
  __shared__ __attribute__((aligned(16))) ushort_t Bbuf[2][256 * 64];  // 64KB

  const int bid = blockIdx.x;  // 512
  const int rowid = bid & 255;
  const int kh = bid >> 8;
  const int lb = ((rowid & 7) << 5) | (rowid >> 3);  // XCD-contiguous (b,h)
  const int b = lb >> 6;
  const int h = lb & 63;
  const int t = threadIdx.x;  // 0..511
  const int wave = t >> 6;
  const int lane = t & 63;
  const int wq = lane >> 4;
  const int wr = lane & 15;
  const int wm = wave >> 2;  // M half
  const int wn = wave & 3;   // N quarter
  const int s_w = t >> 3;    // sampling: w column (0..63)
  const int c8 = t & 7;      // sampling: 8-channel slice (0..7)

  const f32x4 zero = {0.f, 0.f, 0.f, 0.f};
  f32x4 acc[2][4];
  #pragma unroll
  for (int i = 0; i < 2; ++i)
    #pragma unroll
    for (int j = 0; j < 4; ++j) acc[i][j] = zero;

  const ushort_t* xtb = xt + (size_t)b * 4096 * 256;
  const float* offb = off + (size_t)b * 18 * 4096 + h * 64 + s_w;

  if (kh == 0)
    run_gemm<0>(offb, xtb, wb, &Abuf[0][0], &Bbuf[0][0], h, s_w, c8, t, wm, wn, wq, wr, acc);
  else
    run_gemm<1>(offb, xtb, wb, &Abuf[0][0], &Bbuf[0][0], h, s_w, c8, t, wm, wn, wq, wr, acc);

  // ---- epilogue: bf16 partial y write [b][s][o]; D layout col=lane&15,
  // row=(lane>>4)*4+r ----
  ushort_t* yb = (kh ? y1 : y0) + ((size_t)(b * 4096 + h * 64)) * 256;
  #pragma unroll
  for (int tm = 0; tm < 2; ++tm) {
    #pragma unroll
    for (int tn = 0; tn < 4; ++tn) {
      const int o = wn * 64 + tn * 16 + wr;
      #pragma unroll
      for (int r2 = 0; r2 < 4; ++r2) {
        const int ww = wm * 32 + tm * 16 + wq * 4 + r2;
        yb[ww * 256 + o] = f2bf(acc[tm][tn][r2]);
      }
    }
  }
}

// ---------------- combine partials + GN stats ----------------
// yc = y0 + y1 (bf16), stats += {sum, sumsq} per (b, group of 8 o).
__global__ __launch_bounds__(256) void k_comb(const ushort_t* __restrict__ y0,
                                              const ushort_t* __restrict__ y1,
                                              ushort_t* __restrict__ yc,
                                              float* __restrict__ stats) {
  const int bid = blockIdx.x;                    // 256
  const int lb = ((bid & 7) << 5) | (bid >> 3);  // same XCD layout as k_gemm
  const int b = lb >> 6;
  const int sc = lb & 63;  // 64 s-rows per block
  const int t = threadIdx.x;
  const int og = t & 31;  // o-group (8 channels)
  const int s0 = t >> 5;  // 0..7
  const size_t base = ((size_t)(b * 4096 + sc * 64)) * 256 + og * 8;
  float sum = 0.f, ss = 0.f;
  #pragma unroll
  for (int i = 0; i < 8; ++i) {
    const size_t o8 = base + (size_t)(s0 + i * 8) * 256;
    const uint4 a = *(const uint4*)(y0 + o8);
    const uint4 c = *(const uint4*)(y1 + o8);
    uint4 r;
    {
      float vl = bflo(a.x) + bflo(c.x), vh = bfhi(a.x) + bfhi(c.x);
      r.x = f2bf_bits(vl) | (f2bf_bits(vh) << 16);
      sum += vl + vh; ss += vl * vl + vh * vh;
    }
    {
      float vl = bflo(a.y) + bflo(c.y), vh = bfhi(a.y) + bfhi(c.y);
      r.y = f2bf_bits(vl) | (f2bf_bits(vh) << 16);
      sum += vl + vh; ss += vl * vl + vh * vh;
    }
    {
      float vl = bflo(a.z) + bflo(c.z), vh = bfhi(a.z) + bfhi(c.z);
      r.z = f2bf_bits(vl) | (f2bf_bits(vh) << 16);
      sum += vl + vh; ss += vl * vl + vh * vh;
    }
    {
      float vl = bflo(a.w) + bflo(c.w), vh = bfhi(a.w) + bfhi(c.w);
      r.w = f2bf_bits(vl) | (f2bf_bits(vh) << 16);
      sum += vl + vh; ss += vl * vl + vh * vh;
    }
    *(uint4*)(yc + o8) = r;
  }
  // lanes l and l+32 share og -> fold, then one atomic pair per lane<32
  sum += __shfl_xor(sum, 32, 64);
  ss += __shfl_xor(ss, 32, 64);
  if ((t & 63) < 32) {
    atomicAdd(&stats[(b * 32 + og) * 2], sum);
    atomicAdd(&stats[(b * 32 + og) * 2 + 1], ss);
  }
}

// ---------------- GN apply + ReLU, transpose bf16 [b][s][o] -> f32 [b][o][s] ----------------
__global__ __launch_bounds__(256) void k_apply(const ushort_t* __restrict__ yc,
                                               const float* __restrict__ stats,
                                               const float* __restrict__ gamma,
                                               const float* __restrict__ beta,
                                               float* __restrict__ out) {
  __shared__ float tile[64][65];
  __shared__ float sm[8], sr[8], sg[64], sb[64];
  const int bid = blockIdx.x;                    // 1024
  const int lb = ((bid & 7) << 7) | (bid >> 3);  // XCD-contiguous: same b region as k_gemm
  const int b = lb >> 8;
  const int st = (lb >> 2) & 63;
  const int ot = lb & 3;
  const int t = threadIdx.x;
  if (t < 8) {
    const int g = ot * 8 + t;
    const float s1 = stats[(b * 32 + g) * 2];
    const float s2 = stats[(b * 32 + g) * 2 + 1];
    const float mean = s1 * (1.f / 32768.f);
    const float var = s2 * (1.f / 32768.f) - mean * mean;
    sm[t] = mean;
    sr[t] = rsqrtf(var + 1e-5f);
  }
  if (t < 64) {
    sg[t] = gamma[ot * 64 + t];
    sb[t] = beta[ot * 64 + t];
  }
  const ushort_t* yb = yc + ((size_t)(b * 4096 + st * 64)) * 256 + ot * 64;
  #pragma unroll
  for (int i = 0; i < 16; ++i) {
    const int idx = t + 256 * i;
    const int s_l = idx >> 6, o_l = idx & 63;
    tile[s_l][o_l] = bf2f(yb[(size_t)s_l * 256 + o_l]);
  }
  __syncthreads();
  float* ob = out + ((size_t)(b * 256 + ot * 64)) * 4096 + st * 64;
  #pragma unroll
  for (int i = 0; i < 16; ++i) {
    const int idx = t + 256 * i;
    const int o_l = idx >> 6, s_l = idx & 63;
    const int g = o_l >> 3;
    float v = (tile[s_l][o_l] - sm[g]) * sr[g] * sg[o_l] + sb[o_l];
    v = v > 0.f ? v : 0.f;
    ob[(size_t)o_l * 4096 + s_l] = v;
  }
}

extern "C" void kernel_launch(void* const* d_in, const int* in_sizes, int n_in,
                              void* d_out, int out_size, void* d_ws, size_t ws_size,
                              hipStream_t stream) {
  const float* x = (const float*)d_in[0];       // (4,256,64,64)
  const float* off = (const float*)d_in[1];     // (4,18,64,64)
  const float* w = (const float*)d_in[2];       // (256,256,3,3)
  const float* gamma = (const float*)d_in[3];   // (256)
  const float* beta = (const float*)d_in[4];    // (256)
  float* out = (float*)d_out;

  char* ws = (char*)d_ws;
  ushort_t* y0 = (ushort_t*)(ws);                 //  8,388,608 B  partial kh=0, bf16
  ushort_t* y1 = (ushort_t*)(ws + 8388608);       //  8,388,608 B  partial kh=1, bf16
  ushort_t* xt = (ushort_t*)(ws + 16777216);      //  8,388,608 B  [b][h][w][c] bf16
  ushort_t* yc = xt;                              //  reuses xt region after gemm
  ushort_t* wb = (ushort_t*)(ws + 25165824);      //  1,179,648 B  [k][o][c] bf16
  float* stats = (float*)(ws + 26345472);         //      1,024 B  [b][g]{sum,ss}

  hipMemsetAsync(stats, 0, 1024, stream);
  k_prep_w<<<256, 256, 0, stream>>>(w, wb);
  k_prep_x<<<1024, 256, 0, stream>>>(x, xt);
  k_gemm<<<512, 512, 0, stream>>>(off, xt, wb, y0, y1);
  k_comb<<<256, 256, 0, stream>>>(y0, y1, yc, stats);
  k_apply<<<1024, 256, 0, stream>>>(yc, stats, gamma, beta, out);
}

// Round 13
// 85.507 us; speedup vs baseline: 1.0229x; 1.0229x over previous
//
#include <hip/hip_runtime.h>

typedef unsigned short ushort_t;
typedef __bf16 bf16x8 __attribute__((ext_vector_type(8)));
typedef float f32x4 __attribute__((ext_vector_type(4)));
typedef void __attribute__((address_space(1))) gvoid_t;
typedef void __attribute__((address_space(3))) lvoid_t;

__device__ __forceinline__ float bflo(unsigned u) { return __builtin_bit_cast(float, u << 16); }
__device__ __forceinline__ float bfhi(unsigned u) { return __builtin_bit_cast(float, u & 0xffff0000u); }
__device__ __forceinline__ float bf2f(ushort_t v) {
  return __builtin_bit_cast(float, ((unsigned)v) << 16);
}
__device__ __forceinline__ unsigned f2bf_bits(float f) {
  unsigned u = __builtin_bit_cast(unsigned, f);
  return (u + 0x7fffu + ((u >> 16) & 1u)) >> 16;
}
__device__ __forceinline__ ushort_t f2bf(float f) { return (ushort_t)f2bf_bits(f); }

// ---------------- fused prep: x-transpose + w-pack + stats zero (1 launch) ----------------
// blocks 0..1023:  x (b,c,h,w) f32 -> xt[b][h][w][c] bf16
// blocks 1024..1279: w (o,c,k) f32 -> wb[k][o][c] bf16; block 1024 zeroes stats.
__global__ __launch_bounds__(256) void k_prep(const float* __restrict__ x,
                                              const float* __restrict__ w,
                                              ushort_t* __restrict__ xt,
                                              ushort_t* __restrict__ wb,
                                              float* __restrict__ stats) {
  const int gid = blockIdx.x;  // 1280
  const int t = threadIdx.x;
  if (gid >= 1024) {
    if (gid == 1024) stats[t] = 0.f;  // 256 floats = 4b x 32g x {sum,ss}
    const int idx = (gid - 1024) * 256 + t;  // (o,c) pair
    const float* src = w + (size_t)idx * 9;
    #pragma unroll
    for (int k = 0; k < 9; ++k)
      wb[(k << 16) + idx] = f2bf(src[k]);
    return;
  }
  __shared__ ushort_t tile[64][68];
  const int b = gid >> 8;
  const int ct = (gid >> 6) & 3;
  const int pt = gid & 63;
  const float* xb = x + ((size_t)(b * 256 + ct * 64)) * 4096 + pt * 64;
  #pragma unroll
  for (int i = 0; i < 16; ++i) {
    const int idx = t + 256 * i;
    const int c_l = idx >> 6, p_l = idx & 63;
    tile[c_l][p_l] = f2bf(xb[(size_t)c_l * 4096 + p_l]);
  }
  __syncthreads();
  ushort_t* xo = xt + ((size_t)(b * 4096 + pt * 64)) * 256 + ct * 64;
  #pragma unroll
  for (int i = 0; i < 16; ++i) {
    const int idx = t + 256 * i;
    const int p_l = idx >> 6, c_l = idx & 63;
    xo[(size_t)p_l * 256 + c_l] = tile[c_l][p_l];
  }
}

// bilinear meta for one (h, w, tap)
struct SMeta {
  float w00, w01, w10, w11;
  int i00, i01, i10, i11;
};
__device__ __forceinline__ SMeta meta_for(int h, int gw, int k, float oy, float ox) {
  SMeta m;
  const float py = (float)(h - 1 + k / 3) + oy;
  const float px = (float)(gw - 1 + k % 3) + ox;
  const float fy = floorf(py), fx = floorf(px);
  const float ly = py - fy, lx = px - fx;
  const int iy0 = (int)fy, ix0 = (int)fx;
  const float vy0 = (iy0 >= 0 && iy0 < 64) ? 1.f : 0.f;
  const float vy1 = (iy0 >= -1 && iy0 < 63) ? 1.f : 0.f;
  const float vx0 = (ix0 >= 0 && ix0 < 64) ? 1.f : 0.f;
  const float vx1 = (ix0 >= -1 && ix0 < 63) ? 1.f : 0.f;
  m.w00 = (1.f - ly) * (1.f - lx) * vy0 * vx0;
  m.w01 = (1.f - ly) * lx * vy0 * vx1;
  m.w10 = ly * (1.f - lx) * vy1 * vx0;
  m.w11 = ly * lx * vy1 * vx1;
  const int cy0 = min(max(iy0, 0), 63), cy1 = min(max(iy0 + 1, 0), 63);
  const int cx0 = min(max(ix0, 0), 63), cx1 = min(max(ix0 + 1, 0), 63);
  m.i00 = (cy0 * 64 + cx0) * 256;
  m.i01 = (cy0 * 64 + cx1) * 256;
  m.i10 = (cy1 * 64 + cx0) * 256;
  m.i11 = (cy1 * 64 + cx1) * 256;
  return m;
}

__device__ __forceinline__ unsigned lerp_pack(unsigned a, unsigned b, unsigned c, unsigned d,
                                              float w00, float w01, float w10, float w11) {
  float lo = w00 * bflo(a) + w01 * bflo(b) + w10 * bflo(c) + w11 * bflo(d);
  float hi = w00 * bfhi(a) + w01 * bfhi(b) + w10 * bfhi(c) + w11 * bfhi(d);
  return f2bf_bits(lo) | (f2bf_bits(hi) << 16);
}

// ---- K-half GEMM body: 18 chunks, chunk c: tap c>>2, cols (c&3)*64.
// dist-1 prefetch of gathers+B at period start; publish = __syncthreads()'s own
// vmcnt(0)+lgkm(0) drain (robust: no manual waitcnt ledger). ----
template <int KH>
__device__ __forceinline__ void run_gemm(const float* __restrict__ offb,
                                         const ushort_t* __restrict__ xtb,
                                         const ushort_t* __restrict__ wb,
                                         ushort_t* Ab, ushort_t* Bb,
                                         int h, int s_w, int c8, int t,
                                         int wm, int wn, int wq, int wr,
                                         f32x4 (&acc)[2][4]) {
  float oy[5], ox[5];
  #pragma unroll
  for (int i = 0; i < 5; ++i) {
    oy[i] = offb[(2 * (KH * 4 + i)) * 4096];
    ox[i] = offb[(2 * (KH * 4 + i) + 1) * 4096];
  }

#define GATHER(N)                                                \
  {                                                              \
    const int c_ = KH * 18 + (N);                                \
    const int tap_ = c_ >> 2;                                    \
    const int loc_ = tap_ - KH * 4;                              \
    const int c0_ = (c_ & 3) << 6;                               \
    m = meta_for(h, s_w, tap_, oy[loc_], ox[loc_]);              \
    const int cc_ = c0_ + c8 * 8;                                \
    q00 = *(const uint4*)(xtb + m.i00 + cc_);                    \
    q01 = *(const uint4*)(xtb + m.i01 + cc_);                    \
    q10 = *(const uint4*)(xtb + m.i10 + cc_);                    \
    q11 = *(const uint4*)(xtb + m.i11 + cc_);                    \
  }

#define B_ISSUE(N, BUF)                                                                        \
  {                                                                                            \
    const int c_ = KH * 18 + (N);                                                              \
    const int tap_ = c_ >> 2;                                                                  \
    const int c0_ = (c_ & 3) << 6;                                                             \
    _Pragma("unroll") for (int i_ = 0; i_ < 4; ++i_) {                                         \
      const int idx_ = i_ * 512 + t;                                                           \
      const int row_ = idx_ >> 3, slot_ = idx_ & 7;                                            \
      const ushort_t* g_ = wb + (tap_ << 16) + row_ * 256 + c0_ + ((slot_ ^ (row_ & 7)) << 3); \
      __builtin_amdgcn_global_load_lds(                                                        \
          (gvoid_t*)g_, (lvoid_t*)((char*)Bb + (BUF) * 32768 + idx_ * 16), 16, 0, 0);          \
    }                                                                                          \
  }

#define A_WRITE(BUF)                                                         \
  {                                                                          \
    uint4 r;                                                                 \
    r.x = lerp_pack(q00.x, q01.x, q10.x, q11.x, m.w00, m.w01, m.w10, m.w11); \
    r.y = lerp_pack(q00.y, q01.y, q10.y, q11.y, m.w00, m.w01, m.w10, m.w11); \
    r.z = lerp_pack(q00.z, q01.z, q10.z, q11.z, m.w00, m.w01, m.w10, m.w11); \
    r.w = lerp_pack(q00.w, q01.w, q10.w, q11.w, m.w00, m.w01, m.w10, m.w11); \
    *(uint4*)&Ab[(BUF) * 4096 + s_w * 64 + ((c8 ^ (s_w & 7)) << 3)] = r;     \
  }

  {
    SMeta m;
    uint4 q00, q01, q10, q11;
    B_ISSUE(0, 0);
    GATHER(0);
    A_WRITE(0);
  }
  __syncthreads();

  #pragma unroll
  for (int n = 0; n < 18; ++n) {
    const int cur = n & 1;
    const int nb = cur ^ 1;
    SMeta m;
    uint4 q00, q01, q10, q11;
    if (n < 17) {
      B_ISSUE(n + 1, nb);
      GATHER(n + 1);
    }
    #pragma unroll
    for (int ks = 0; ks < 2; ++ks) {
      bf16x8 af[2], bfr[4];
      #pragma unroll
      for (int tm = 0; tm < 2; ++tm) {
        const int row = wm * 32 + tm * 16 + wr;
        const int slot = (ks * 4 + wq) ^ (row & 7);
        af[tm] = *(const bf16x8*)&Ab[cur * 4096 + row * 64 + slot * 8];
      }
      #pragma unroll
      for (int tn = 0; tn < 4; ++tn) {
        const int row = wn * 64 + tn * 16 + wr;
        const int slot = (ks * 4 + wq) ^ (row & 7);
        bfr[tn] = *(const bf16x8*)&Bb[cur * 16384 + row * 64 + slot * 8];
      }
      __builtin_amdgcn_s_setprio(1);  // T5: role diversity exists (2 indep blocks/CU)
      #pragma unroll
      for (int tm = 0; tm < 2; ++tm)
        #pragma unroll
        for (int tn = 0; tn < 4; ++tn)
          acc[tm][tn] =
              __builtin_amdgcn_mfma_f32_16x16x32_bf16(af[tm], bfr[tn], acc[tm][tn], 0, 0, 0);
      __builtin_amdgcn_s_setprio(0);
    }
    if (n < 17) {
      A_WRITE(nb);
      __syncthreads();
    }
  }
#undef GATHER
#undef B_ISSUE
#undef A_WRITE
}

// ---------------- fused deform-sample + GEMM, K-split bf16 partials ----------------
// grid = 512: rowid=bid&255 -> (b,h) XCD-swizzled; kh=bid>>8. BM=64, BN=256,
// 8 waves. LDS 80KB -> 2 INDEPENDENT blocks/CU (m114 overlap mechanism).
__global__ __launch_bounds__(512) void k_gemm(const float* __restrict__ off,
                                              const ushort_t* __restrict__ xt,
                                              const ushort_t* __restrict__ wb,
                                              ushort_t* __restrict__ y0,
                                              ushort_t* __restrict__ y1) {
  __shared__ __attribute__((aligned(16))) ushort_t Abuf[2][64 * 64];   // 16KB
  __shared__ __attribute__((aligned(16))) ushort_t Bbuf[2][256 * 64];  // 64KB

  const int bid = blockIdx.x;  // 512
  const int rowid = bid & 255;
  const int kh = bid >> 8;
  const int lb = ((rowid & 7) << 5) | (rowid >> 3);  // XCD-contiguous (b,h)
  const int b = lb >> 6;
  const int h = lb & 63;
  const int t = threadIdx.x;
  const int wave = t >> 6;
  const int lane = t & 63;
  const int wq = lane >> 4;
  const int wr = lane & 15;
  const int wm = wave >> 2;
  const int wn = wave & 3;
  const int s_w = t >> 3;
  const int c8 = t & 7;

  const f32x4 zero = {0.f, 0.f, 0.f, 0.f};
  f32x4 acc[2][4];
  #pragma unroll
  for (int i = 0; i < 2; ++i)
    #pragma unroll
    for (int j = 0; j < 4; ++j) acc[i][j] = zero;

  const ushort_t* xtb = xt + (size_t)b * 4096 * 256;
  const float* offb = off + (size_t)b * 18 * 4096 + h * 64 + s_w;

  if (kh == 0)
    run_gemm<0>(offb, xtb, wb, &Abuf[0][0], &Bbuf[0][0], h, s_w, c8, t, wm, wn, wq, wr, acc);
  else
    run_gemm<1>(offb, xtb, wb, &Abuf[0][0], &Bbuf[0][0], h, s_w, c8, t, wm, wn, wq, wr, acc);

  ushort_t* yb = (kh ? y1 : y0) + ((size_t)(b * 4096 + h * 64)) * 256;
  #pragma unroll
  for (int tm = 0; tm < 2; ++tm) {
    #pragma unroll
    for (int tn = 0; tn < 4; ++tn) {
      const int o = wn * 64 + tn * 16 + wr;
      #pragma unroll
      for (int r2 = 0; r2 < 4; ++r2) {
        const int ww = wm * 32 + tm * 16 + wq * 4 + r2;
        yb[ww * 256 + o] = f2bf(acc[tm][tn][r2]);
      }
    }
  }
}

// ---------------- combine partials + GN stats + transpose to [b][o][s] ----------------
// block = (b, st, ot): 64s x 64o tile. Vectorized uint4 reads of y0,y1 (8 bf16),
// f32 add, stats partials (each uint4 spans exactly one 8-wide o-group),
// LDS transpose, write yc[b][o][s] bf16 (apply becomes pure streaming).
__global__ __launch_bounds__(256) void k_comb(const ushort_t* __restrict__ y0,
                                              const ushort_t* __restrict__ y1,
                                              ushort_t* __restrict__ yc,
                                              float* __restrict__ stats) {
  __shared__ float tile[64][65];
  const int bid = blockIdx.x;                    // 1024
  const int lb = ((bid & 7) << 7) | (bid >> 3);  // XCD-contiguous
  const int b = lb >> 8;
  const int st = (lb >> 2) & 63;
  const int ot = lb & 3;
  const int t = threadIdx.x;
  const size_t ybase = ((size_t)(b * 4096 + st * 64)) * 256 + ot * 64;
  float sum = 0.f, ss = 0.f;
  #pragma unroll
  for (int i = 0; i < 2; ++i) {
    const int u = t + 256 * i;
    const int s_l = u >> 3;  // 0..63
    const int o8 = u & 7;    // 8-wide o-subgroup
    const size_t adr = ybase + (size_t)s_l * 256 + o8 * 8;
    const uint4 a = *(const uint4*)(y0 + adr);
    const uint4 c = *(const uint4*)(y1 + adr);
    float v[8];
    v[0] = bflo(a.x) + bflo(c.x); v[1] = bfhi(a.x) + bfhi(c.x);
    v[2] = bflo(a.y) + bflo(c.y); v[3] = bfhi(a.y) + bfhi(c.y);
    v[4] = bflo(a.z) + bflo(c.z); v[5] = bfhi(a.z) + bfhi(c.z);
    v[6] = bflo(a.w) + bflo(c.w); v[7] = bfhi(a.w) + bfhi(c.w);
    #pragma unroll
    for (int j = 0; j < 8; ++j) {
      sum += v[j];
      ss += v[j] * v[j];
      tile[s_l][o8 * 8 + j] = v[j];
    }
  }
  // group of this thread = ot*8 + (t&7); fold lanes differing in bits 3,4,5
  #pragma unroll
  for (int d = 8; d < 64; d <<= 1) {
    sum += __shfl_xor(sum, d, 64);
    ss += __shfl_xor(ss, d, 64);
  }
  if ((t & 63) < 8) {
    const int g = ot * 8 + (t & 7);
    atomicAdd(&stats[(b * 32 + g) * 2], sum);
    atomicAdd(&stats[(b * 32 + g) * 2 + 1], ss);
  }
  __syncthreads();
  // transposed write: 8 s per thread for one o
  #pragma unroll
  for (int i = 0; i < 2; ++i) {
    const int u = t + 256 * i;
    const int o_l = u >> 3;  // 0..63
    const int s8 = u & 7;
    float v[8];
    #pragma unroll
    for (int j = 0; j < 8; ++j) v[j] = tile[s8 * 8 + j][o_l];
    uint4 r;
    r.x = f2bf_bits(v[0]) | (f2bf_bits(v[1]) << 16);
    r.y = f2bf_bits(v[2]) | (f2bf_bits(v[3]) << 16);
    r.z = f2bf_bits(v[4]) | (f2bf_bits(v[5]) << 16);
    r.w = f2bf_bits(v[6]) | (f2bf_bits(v[7]) << 16);
    *(uint4*)(yc + ((size_t)(b * 256 + ot * 64 + o_l)) * 4096 + st * 64 + s8 * 8) = r;
  }
}

// ---------------- GN apply + ReLU: pure streaming over [b][o][s] ----------------
__global__ __launch_bounds__(256) void k_apply(const ushort_t* __restrict__ yc,
                                               const float* __restrict__ stats,
                                               const float* __restrict__ gamma,
                                               const float* __restrict__ beta,
                                               float* __restrict__ out) {
  const int bid = blockIdx.x;                    // 2048
  const int lb = ((bid & 7) << 8) | (bid >> 3);  // XCD-contiguous
  const size_t base = (size_t)lb * 2048 + threadIdx.x * 8;  // element index
  const int b = (int)(base >> 20);
  const int o = (int)((base >> 12) & 255);
  const int g = o >> 3;
  const float s1 = stats[(b * 32 + g) * 2];
  const float s2 = stats[(b * 32 + g) * 2 + 1];
  const float mean = s1 * (1.f / 32768.f);
  const float var = s2 * (1.f / 32768.f) - mean * mean;
  const float rstd = rsqrtf(var + 1e-5f);
  const float sc = rstd * gamma[o];
  const float sh = beta[o] - mean * sc;
  const uint4 a = *(const uint4*)(yc + base);
  float v[8];
  v[0] = bflo(a.x); v[1] = bfhi(a.x);
  v[2] = bflo(a.y); v[3] = bfhi(a.y);
  v[4] = bflo(a.z); v[5] = bfhi(a.z);
  v[6] = bflo(a.w); v[7] = bfhi(a.w);
  float4 f0, f1;
  f0.x = fmaxf(v[0] * sc + sh, 0.f);
  f0.y = fmaxf(v[1] * sc + sh, 0.f);
  f0.z = fmaxf(v[2] * sc + sh, 0.f);
  f0.w = fmaxf(v[3] * sc + sh, 0.f);
  f1.x = fmaxf(v[4] * sc + sh, 0.f);
  f1.y = fmaxf(v[5] * sc + sh, 0.f);
  f1.z = fmaxf(v[6] * sc + sh, 0.f);
  f1.w = fmaxf(v[7] * sc + sh, 0.f);
  *(float4*)(out + base) = f0;
  *(float4*)(out + base + 4) = f1;
}

extern "C" void kernel_launch(void* const* d_in, const int* in_sizes, int n_in,
                              void* d_out, int out_size, void* d_ws, size_t ws_size,
                              hipStream_t stream) {
  const float* x = (const float*)d_in[0];       // (4,256,64,64)
  const float* off = (const float*)d_in[1];     // (4,18,64,64)
  const float* w = (const float*)d_in[2];       // (256,256,3,3)
  const float* gamma = (const float*)d_in[3];   // (256)
  const float* beta = (const float*)d_in[4];    // (256)
  float* out = (float*)d_out;

  char* ws = (char*)d_ws;
  ushort_t* y0 = (ushort_t*)(ws);                 //  8,388,608 B  partial kh=0, bf16
  ushort_t* y1 = (ushort_t*)(ws + 8388608);       //  8,388,608 B  partial kh=1, bf16
  ushort_t* xt = (ushort_t*)(ws + 16777216);      //  8,388,608 B  [b][h][w][c] bf16
  ushort_t* yc = xt;                              //  reuses xt region after gemm
  ushort_t* wb = (ushort_t*)(ws + 25165824);      //  1,179,648 B  [k][o][c] bf16
  float* stats = (float*)(ws + 26345472);         //      1,024 B  [b][g]{sum,ss}

  k_prep<<<1280, 256, 0, stream>>>(x, w, xt, wb, stats);
  k_gemm<<<512, 512, 0, stream>>>(off, xt, wb, y0, y1);
  k_comb<<<1024, 256, 0, stream>>>(y0, y1, yc, stats);
  k_apply<<<2048, 256, 0, stream>>>(yc, stats, gamma, beta, out);
}